// Round 1
// baseline (442.768 us; speedup 1.0000x reference)
//
#include <hip/hip_runtime.h>
#include <math.h>

#define B_   8
#define C_   32
#define H_   256
#define W_   256
#define HID_ 64
#define NPIX (B_*C_*H_*W_)   // 16777216 = offset of logdet in d_out

// ---------------------------------------------------------------------------
// Prep: weight-norm both convs, transpose for the main kernel, zero logdet.
//   w1t layout: [(c*6+k)*64 + o]  (k = kh*3+kw)
//   w2L layout: [j*64 + o]
// ---------------------------------------------------------------------------
__global__ __launch_bounds__(64) void prep_kernel(
    const float* __restrict__ v1, const float* __restrict__ g1,
    const float* __restrict__ v2, const float* __restrict__ g2,
    float* __restrict__ w1t, float* __restrict__ w2L,
    float* __restrict__ logdet)
{
    const int t   = threadIdx.x;   // 0..63
    const int bid = blockIdx.x;    // 0..127
    if (bid < 64) {
        const int o = bid;                       // out channel of conv1
        // v1[o] has 192 elements (c*6+k); 3 per thread
        float a0 = v1[o*192 + t];
        float a1 = v1[o*192 + t + 64];
        float a2 = v1[o*192 + t + 128];
        float s  = a0*a0 + a1*a1 + a2*a2;
        #pragma unroll
        for (int m = 32; m >= 1; m >>= 1) s += __shfl_xor(s, m, 64);
        const float inv = g1[o] / sqrtf(s);
        w1t[(t      )*64 + o] = a0 * inv;
        w1t[(t +  64)*64 + o] = a1 * inv;
        w1t[(t + 128)*64 + o] = a2 * inv;
        if (bid == 0 && t < B_) logdet[t] = 0.f;   // zero logdet every launch
    } else {
        const int j = bid - 64;                  // out channel of conv2
        float a = v2[j*64 + t];
        float s = a*a;
        #pragma unroll
        for (int m = 32; m >= 1; m >>= 1) s += __shfl_xor(s, m, 64);
        const float inv = g2[j] / sqrtf(s);
        w2L[j*64 + t] = a * inv;
    }
}

// ---------------------------------------------------------------------------
// Fused main kernel: one block per (b, h) output row; one thread per w.
// ---------------------------------------------------------------------------
__global__ __launch_bounds__(256) void flow_kernel(
    const float* __restrict__ x,
    const float* __restrict__ w1t, const float* __restrict__ w2L,
    const float* __restrict__ b1,  const float* __restrict__ b2,
    float* __restrict__ out, float* __restrict__ logdet)
{
    const int bi = blockIdx.x;
    const int b  = bi >> 8;          // batch
    const int h  = bi & 255;         // output row
    const int w  = threadIdx.x;      // output col (0..255)

    const float* xb = x + (size_t)b * C_ * H_ * W_;

    // ---- conv1: 2x3 causal conv, C=32 -> HID=64 --------------------------
    float acc[HID_];
    #pragma unroll
    for (int o = 0; o < HID_; ++o) acc[o] = b1[o];

    const bool r0v = (h >= 2);   // row h-2 valid  (uniform per block)
    const bool r1v = (h >= 1);   // row h-1 valid

    for (int c = 0; c < C_; ++c) {
        float xv[6];
        if (r0v) {
            const float* p = xb + ((size_t)c*H_ + (h-2))*W_;
            xv[0] = (w > 0)      ? p[w-1] : 0.f;
            xv[1] = p[w];
            xv[2] = (w < W_-1)   ? p[w+1] : 0.f;
        } else { xv[0] = xv[1] = xv[2] = 0.f; }
        if (r1v) {
            const float* p = xb + ((size_t)c*H_ + (h-1))*W_;
            xv[3] = (w > 0)      ? p[w-1] : 0.f;
            xv[4] = p[w];
            xv[5] = (w < W_-1)   ? p[w+1] : 0.f;
        } else { xv[3] = xv[4] = xv[5] = 0.f; }

        const float* wp = w1t + c*6*64;   // uniform address -> scalar loads
        #pragma unroll
        for (int k = 0; k < 6; ++k) {
            const float xk = xv[k];
            #pragma unroll
            for (int o = 0; o < HID_; ++o)
                acc[o] += xk * wp[k*64 + o];
        }
    }

    // ---- ELU -------------------------------------------------------------
    #pragma unroll
    for (int o = 0; o < HID_; ++o) {
        const float a = acc[o];
        acc[o] = (a > 0.f) ? a : expm1f(a);
    }

    // ---- conv2 (1x1, 64 -> 64): first 32 channels = mu -------------------
    float mu[C_];
    #pragma unroll
    for (int j = 0; j < C_; ++j) {
        const float* wj = w2L + j*64;     // uniform -> scalar loads
        float s = b2[j];
        #pragma unroll
        for (int o = 0; o < HID_; ++o) s += acc[o] * wj[o];
        mu[j] = s;
    }

    // ---- conv2 second half -> scale, affine flow, logdet -----------------
    float ldsum = 0.f;
    float* ob = out + (size_t)b * C_ * H_ * W_;
    #pragma unroll
    for (int j = 0; j < C_; ++j) {
        const float* wj = w2L + (C_ + j)*64;
        float s = b2[C_ + j];
        #pragma unroll
        for (int o = 0; o < HID_; ++o) s += acc[o] * wj[o];
        const float z  = s + 2.f;
        const float sc = 1.f / (1.f + __expf(-z));   // sigmoid
        ldsum += __logf(sc);
        const size_t idx = ((size_t)j*H_ + h)*W_ + w;
        ob[idx] = xb[idx] * sc + mu[j];
    }

    // ---- block reduction of logdet ---------------------------------------
    #pragma unroll
    for (int m = 32; m >= 1; m >>= 1) ldsum += __shfl_xor(ldsum, m, 64);
    __shared__ float red[4];
    const int wid  = threadIdx.x >> 6;
    const int lane = threadIdx.x & 63;
    if (lane == 0) red[wid] = ldsum;
    __syncthreads();
    if (threadIdx.x == 0) {
        const float s = red[0] + red[1] + red[2] + red[3];
        atomicAdd(&logdet[b], s);
    }
}

// ---------------------------------------------------------------------------
extern "C" void kernel_launch(void* const* d_in, const int* in_sizes, int n_in,
                              void* d_out, int out_size, void* d_ws, size_t ws_size,
                              hipStream_t stream)
{
    const float* x  = (const float*)d_in[0];
    const float* v1 = (const float*)d_in[1];
    const float* g1 = (const float*)d_in[2];
    const float* b1 = (const float*)d_in[3];
    const float* v2 = (const float*)d_in[4];
    const float* g2 = (const float*)d_in[5];
    const float* b2 = (const float*)d_in[6];

    float* out    = (float*)d_out;
    float* logdet = out + NPIX;

    float* w1t = (float*)d_ws;          // 12288 floats
    float* w2L = w1t + 12288;           //  4096 floats (total 64 KiB)

    prep_kernel<<<128, 64, 0, stream>>>(v1, g1, v2, g2, w1t, w2L, logdet);
    flow_kernel<<<B_ * H_, W_, 0, stream>>>(x, w1t, w2L, b1, b2, out, logdet);
}

// Round 2
// 113.485 us; speedup vs baseline: 3.9016x; 3.9016x over previous
//
#include <hip/hip_runtime.h>
#include <hip/hip_bf16.h>
#include <math.h>

#define B_   8
#define C_   32
#define H_   256
#define W_   256
#define HID_ 64
#define NPIX (B_*C_*H_*W_)   // offset of logdet in d_out

typedef __attribute__((ext_vector_type(8))) short short8;   // bf16x8 MFMA A/B frag
typedef __attribute__((ext_vector_type(4))) float f32x4;    // fp32x4 MFMA C/D frag

static __device__ __forceinline__ short f2bf(float f) {
    __hip_bfloat16 h = __float2bfloat16(f);           // RNE
    union { __hip_bfloat16 h; short s; } u; u.h = h; return u.s;
}
static __device__ __forceinline__ float bf2f(unsigned short u) {
    return __uint_as_float(((unsigned)u) << 16);
}

// ---------------------------------------------------------------------------
// Prep: weight-norm, convert to bf16, permute for MFMA B-frag reads.
//   w1b[o*192 + tap*32 + c]  (tap = kh*3+kw)   w2b[j*64 + o]
// ---------------------------------------------------------------------------
__global__ __launch_bounds__(64) void prep_kernel(
    const float* __restrict__ v1, const float* __restrict__ g1,
    const float* __restrict__ v2, const float* __restrict__ g2,
    short* __restrict__ w1b, short* __restrict__ w2b,
    float* __restrict__ logdet)
{
    const int t   = threadIdx.x;   // 0..63
    const int bid = blockIdx.x;    // 0..127
    if (bid < 64) {
        const int o = bid;
        float a0 = v1[o*192 + t];
        float a1 = v1[o*192 + t + 64];
        float a2 = v1[o*192 + t + 128];
        float s  = a0*a0 + a1*a1 + a2*a2;
        #pragma unroll
        for (int m = 32; m >= 1; m >>= 1) s += __shfl_xor(s, m, 64);
        const float inv = g1[o] / sqrtf(s);
        const int e0 = t, e1 = t + 64, e2 = t + 128;   // src idx = c*6 + tap
        w1b[o*192 + (e0%6)*32 + e0/6] = f2bf(a0*inv);
        w1b[o*192 + (e1%6)*32 + e1/6] = f2bf(a1*inv);
        w1b[o*192 + (e2%6)*32 + e2/6] = f2bf(a2*inv);
        if (bid == 0 && t < B_) logdet[t] = 0.f;       // zero logdet every launch
    } else {
        const int j = bid - 64;
        float a = v2[j*64 + t];
        float s = a*a;
        #pragma unroll
        for (int m = 32; m >= 1; m >>= 1) s += __shfl_xor(s, m, 64);
        const float inv = g2[j] / sqrtf(s);
        w2b[j*64 + t] = f2bf(a*inv);
    }
}

// ---------------------------------------------------------------------------
// Fused MFMA kernel: one block per (b, h) row. 4 waves, each owns 64 pixels.
// LDS region R0 (32 KiB) is reused: sA (staged x rows) -> hL -> mu/z.
//   sA byte(r,w,c)  = r*16384 + w*64  + ((c>>3) ^ ((w>>1)&3))*16 + (c&7)*2
//   hL byte(px,o)   =            px*128 + ((o>>3) ^ (px&7))*16   + (o&7)*2
// ---------------------------------------------------------------------------
__global__ __launch_bounds__(256) void flow_kernel(
    const float* __restrict__ x,
    const short* __restrict__ w1b, const short* __restrict__ w2b,
    const float* __restrict__ b1,  const float* __restrict__ b2,
    float* __restrict__ out, float* __restrict__ logdet)
{
    __shared__ int ldsI[8192];     // 32 KiB
    __shared__ float red4[4];

    const int bi0 = blockIdx.x;
    const int bi  = (bi0 & 7) * 256 + (bi0 >> 3);   // XCD-chunked: XCD k owns image k
    const int b   = bi >> 8;
    const int h   = bi & 255;
    const int tid  = threadIdx.x;
    const int l    = tid & 63;
    const int wv   = tid >> 6;
    const int lrow = l & 15;
    const int lk   = l >> 4;

    const float* xb = x + (size_t)b * (C_*H_*W_);
    short* ldsS = (short*)ldsI;

    // ---- Phase A: stage rows h-2, h-1 (bf16, swizzled, transposed) --------
    {
        const int w   = tid;            // 0..255
        const int swz = (w >> 1) & 3;
        #pragma unroll
        for (int r = 0; r < 2; ++r) {
            const int hr   = h - 2 + r;
            const int base = r*4096 + w*16;            // dword index of row
            if (hr >= 0) {
                #pragma unroll
                for (int cp = 0; cp < 16; ++cp) {      // channel pair 2cp,2cp+1
                    const float x0 = xb[((size_t)(2*cp)   * H_ + hr) * W_ + w];
                    const float x1 = xb[((size_t)(2*cp+1) * H_ + hr) * W_ + w];
                    const int val = (int)(unsigned short)f2bf(x0)
                                  | ((int)(unsigned short)f2bf(x1) << 16);
                    ldsI[base + ((cp>>2) ^ swz)*4 + (cp & 3)] = val;
                }
            } else {
                #pragma unroll
                for (int cp = 0; cp < 16; ++cp)
                    ldsI[base + ((cp>>2) ^ swz)*4 + (cp & 3)] = 0;
            }
        }
    }
    __syncthreads();

    // ---- Phase B: conv1 (2x3, C=32 -> 64) via MFMA ------------------------
    f32x4 acc1[4][4];
    #pragma unroll
    for (int nt = 0; nt < 4; ++nt) {
        const float bv = b1[nt*16 + lrow];
        #pragma unroll
        for (int mt = 0; mt < 4; ++mt) acc1[mt][nt] = (f32x4){bv, bv, bv, bv};
    }

    const short8 zero8 = {0,0,0,0,0,0,0,0};
    #pragma unroll
    for (int tap = 0; tap < 6; ++tap) {
        const int r  = tap / 3;          // kh  -> staged row r
        const int dw = (tap % 3) - 1;    // kw-1
        short8 bf[4];
        #pragma unroll
        for (int nt = 0; nt < 4; ++nt)
            bf[nt] = *(const short8*)(w1b + (nt*16 + lrow)*192 + tap*32 + lk*8);
        #pragma unroll
        for (int mt = 0; mt < 4; ++mt) {
            const int pxo = wv*64 + mt*16 + lrow;          // output col
            const int px  = pxo + dw;                      // input col
            const int pxc = px < 0 ? 0 : (px > 255 ? 255 : px);
            const int byte = r*16384 + pxc*64 + ((lk ^ ((pxc>>1)&3))*16);
            short8 af = *(const short8*)((const char*)ldsI + byte);
            if (px != pxc) af = zero8;                     // column zero-pad
            #pragma unroll
            for (int nt = 0; nt < 4; ++nt)
                acc1[mt][nt] = __builtin_amdgcn_mfma_f32_16x16x32_bf16(
                                   af, bf[nt], acc1[mt][nt], 0, 0, 0);
        }
    }
    __syncthreads();   // all sA reads done; R0 becomes hL

    // ---- Phase C: ELU -> bf16 -> hL (wave-private px range) ---------------
    #pragma unroll
    for (int mt = 0; mt < 4; ++mt) {
        #pragma unroll
        for (int reg = 0; reg < 4; ++reg) {
            const int px    = wv*64 + mt*16 + lk*4 + reg;
            const int pbase = px*64;        // in shorts
            const int pswz  = px & 7;
            #pragma unroll
            for (int nt = 0; nt < 4; ++nt) {
                float v = acc1[mt][nt][reg];
                v = v > 0.f ? v : expm1f(v);
                const int o = nt*16 + lrow;
                ldsS[pbase + (((o>>3) ^ pswz) << 3) + (o & 7)] = f2bf(v);
            }
        }
    }
    __syncthreads();

    // ---- Phase D: conv2 (1x1, 64 -> 64) via MFMA --------------------------
    f32x4 acc2[4][4];
    #pragma unroll
    for (int mt = 0; mt < 4; ++mt)
        #pragma unroll
        for (int nt = 0; nt < 4; ++nt) acc2[mt][nt] = (f32x4){0.f,0.f,0.f,0.f};

    #pragma unroll
    for (int kt = 0; kt < 2; ++kt) {
        short8 bf[4];
        #pragma unroll
        for (int nt = 0; nt < 4; ++nt)
            bf[nt] = *(const short8*)(w2b + (nt*16 + lrow)*64 + kt*32 + lk*8);
        #pragma unroll
        for (int mt = 0; mt < 4; ++mt) {
            const int px   = wv*64 + mt*16 + lrow;
            const int byte = px*128 + (((kt*4 + lk) ^ (px & 7))*16);
            short8 af = *(const short8*)((const char*)ldsI + byte);
            #pragma unroll
            for (int nt = 0; nt < 4; ++nt)
                acc2[mt][nt] = __builtin_amdgcn_mfma_f32_16x16x32_bf16(
                                   af, bf[nt], acc2[mt][nt], 0, 0, 0);
        }
    }

    // ---- Phase E: transpose mu/z through R0, then coalesced epilogue ------
    #pragma unroll
    for (int mt = 0; mt < 4; ++mt) {
        #pragma unroll
        for (int reg = 0; reg < 4; ++reg) {
            const int px    = wv*64 + mt*16 + lk*4 + reg;
            const int pbase = px*64;
            const int pswz  = px & 7;
            #pragma unroll
            for (int nt = 0; nt < 4; ++nt) {
                const int j = nt*16 + lrow;     // 0..63 : <32 mu, >=32 log_scale
                ldsS[pbase + (((j>>3) ^ pswz) << 3) + (j & 7)] = f2bf(acc2[mt][nt][reg]);
            }
        }
    }
    __syncthreads();

    {
        const int w     = tid;
        const int pswz  = w & 7;
        float ldsum = 0.f;
        float* ob = out + (size_t)b * (C_*H_*W_);
        #pragma unroll
        for (int j = 0; j < 32; j += 2) {
            const int mi = (w*64 + (((j>>3)     ^ pswz) << 3) + (j & 7)) >> 1;
            const int zi = (w*64 + ((((j>>3)+4) ^ pswz) << 3) + (j & 7)) >> 1;
            const int mraw = ldsI[mi];
            const int zraw = ldsI[zi];
            const float mu0 = bf2f((unsigned short)(mraw & 0xffff))      + b2[j];
            const float mu1 = bf2f((unsigned short)((unsigned)mraw >> 16)) + b2[j+1];
            const float z0  = bf2f((unsigned short)(zraw & 0xffff))      + b2[j+32] + 2.f;
            const float z1  = bf2f((unsigned short)((unsigned)zraw >> 16)) + b2[j+33] + 2.f;
            const float sc0 = 1.f / (1.f + __expf(-z0));
            const float sc1 = 1.f / (1.f + __expf(-z1));
            ldsum += __logf(sc0) + __logf(sc1);
            const size_t i0 = ((size_t)j     * H_ + h) * W_ + w;
            const size_t i1 = ((size_t)(j+1) * H_ + h) * W_ + w;
            ob[i0] = xb[i0] * sc0 + mu0;
            ob[i1] = xb[i1] * sc1 + mu1;
        }
        #pragma unroll
        for (int m = 32; m >= 1; m >>= 1) ldsum += __shfl_xor(ldsum, m, 64);
        if (l == 0) red4[wv] = ldsum;
        __syncthreads();
        if (tid == 0) atomicAdd(&logdet[b], red4[0]+red4[1]+red4[2]+red4[3]);
    }
}

// ---------------------------------------------------------------------------
extern "C" void kernel_launch(void* const* d_in, const int* in_sizes, int n_in,
                              void* d_out, int out_size, void* d_ws, size_t ws_size,
                              hipStream_t stream)
{
    const float* x  = (const float*)d_in[0];
    const float* v1 = (const float*)d_in[1];
    const float* g1 = (const float*)d_in[2];
    const float* b1 = (const float*)d_in[3];
    const float* v2 = (const float*)d_in[4];
    const float* g2 = (const float*)d_in[5];
    const float* b2 = (const float*)d_in[6];

    float* out    = (float*)d_out;
    float* logdet = out + NPIX;

    short* w1b = (short*)d_ws;          // 12288 bf16 (24,576 B)
    short* w2b = w1b + 12288;           //  4096 bf16 ( 8,192 B)

    prep_kernel<<<128, 64, 0, stream>>>(v1, g1, v2, g2, w1b, w2b, logdet);
    flow_kernel<<<B_ * H_, 256, 0, stream>>>(x, w1b, w2b, b1, b2, out, logdet);
}

// Round 3
// 71.196 us; speedup vs baseline: 6.2190x; 1.5940x over previous
//
#include <hip/hip_runtime.h>
#include <hip/hip_bf16.h>
#include <math.h>

#define B_   8
#define C_   32
#define H_   256
#define W_   256
#define NPIX (B_*C_*H_*W_)   // offset of logdet in d_out

typedef __attribute__((ext_vector_type(8))) short short8;   // bf16x8 MFMA A/B frag
typedef __attribute__((ext_vector_type(4))) float f32x4;    // fp32x4 MFMA C/D frag
typedef __attribute__((ext_vector_type(2))) float f32x2;

static __device__ __forceinline__ short f2bf(float f) {
    union { __hip_bfloat16 h; short s; } u; u.h = __float2bfloat16(f); return u.s;
}

// ---------------------------------------------------------------------------
// Prep: weight-norm -> bf16.
//   w1b[o*192 + tap*32 + c]                       (tap = kh*3+kw)
//   w2b[j*64 + slot],  slot permutation chosen so conv2 B-frags are built
//   lane-locally from conv1's D-registers:
//     channel c (mt=c>>4, q=(c>>2)&3, reg=c&3) -> slot (mt>>1)*32+q*8+(mt&1)*4+reg
// ---------------------------------------------------------------------------
__global__ __launch_bounds__(64) void prep_kernel(
    const float* __restrict__ v1, const float* __restrict__ g1,
    const float* __restrict__ v2, const float* __restrict__ g2,
    short* __restrict__ w1b, short* __restrict__ w2b,
    float* __restrict__ logdet)
{
    const int t   = threadIdx.x;   // 0..63
    const int bid = blockIdx.x;    // 0..127
    if (bid < 64) {
        const int o = bid;
        float a0 = v1[o*192 + t];
        float a1 = v1[o*192 + t + 64];
        float a2 = v1[o*192 + t + 128];
        float s  = a0*a0 + a1*a1 + a2*a2;
        #pragma unroll
        for (int m = 32; m >= 1; m >>= 1) s += __shfl_xor(s, m, 64);
        const float inv = g1[o] / sqrtf(s);
        const int e0 = t, e1 = t + 64, e2 = t + 128;   // src idx = c*6 + tap
        w1b[o*192 + (e0%6)*32 + e0/6] = f2bf(a0*inv);
        w1b[o*192 + (e1%6)*32 + e1/6] = f2bf(a1*inv);
        w1b[o*192 + (e2%6)*32 + e2/6] = f2bf(a2*inv);
        if (bid == 0 && t < B_) logdet[t] = 0.f;       // zero logdet every launch
    } else {
        const int j = bid - 64;
        float a = v2[j*64 + t];
        float s = a*a;
        #pragma unroll
        for (int m = 32; m >= 1; m >>= 1) s += __shfl_xor(s, m, 64);
        const float inv = g2[j] / sqrtf(s);
        const int mt = t >> 4, r = t & 15;
        const int slot = (mt >> 1)*32 + ((r >> 2) << 3) + ((mt & 1) << 2) + (r & 3);
        w2b[j*64 + slot] = f2bf(a*inv);
    }
}

// ---------------------------------------------------------------------------
// Fused MFMA kernel: one block per (b, h) row; 4 waves, each owns 64 pixels.
// conv1: D1[o][px] = W1 . Xpatch  (A = weights, B = x)  -> lane: o=4q+reg, px=lrow
// conv2: in-register B-frag (permuted hidden dim), D2[j][px] same lane layout.
// LDS: only the staged input rows (h-2, h-1), bf16, swizzled:
//   byte(r,w,c) = r*16384 + w*64 + ((c>>3)^((w>>1)&3))*16 + (c&7)*2
// ---------------------------------------------------------------------------
__global__ __launch_bounds__(256) void flow_kernel(
    const float* __restrict__ x,
    const short* __restrict__ w1b, const short* __restrict__ w2b,
    const float* __restrict__ b1,  const float* __restrict__ b2,
    float* __restrict__ out, float* __restrict__ logdet)
{
    __shared__ int ldsI[8192];     // 32 KiB
    __shared__ float red4[4];

    const int bi0 = blockIdx.x;
    const int bi  = (bi0 & 7) * 256 + (bi0 >> 3);   // XCD k owns image k
    const int b   = bi >> 8;
    const int h   = bi & 255;
    const int tid  = threadIdx.x;
    const int l    = tid & 63;
    const int wv   = tid >> 6;
    const int lrow = l & 15;
    const int q    = l >> 4;

    const float* xb = x + (size_t)b * (C_*H_*W_);

    // ---- Phase A: stage rows h-2, h-1 (bf16, swizzled, c-contiguous) ------
    {
        const int r   = tid >> 7;            // threads 0-127: row h-2; 128-255: h-1
        const int w0  = (tid & 127) << 1;    // pixel pair w0, w0+1
        const int hr  = h - 2 + r;
        const int swz = (w0 >> 1) & 3;
        const int base = r*4096 + w0*16;     // dword index
        if (hr >= 0) {
            const float* pr = xb + (size_t)hr * W_ + w0;
            #pragma unroll
            for (int cp = 0; cp < 16; ++cp) {
                f32x2 a0 = *(const f32x2*)(pr + (size_t)(2*cp  ) * (H_*W_));
                f32x2 a1 = *(const f32x2*)(pr + (size_t)(2*cp+1) * (H_*W_));
                const int lo = (int)(unsigned short)f2bf(a0[0]) | ((int)(unsigned short)f2bf(a1[0]) << 16);
                const int hi = (int)(unsigned short)f2bf(a0[1]) | ((int)(unsigned short)f2bf(a1[1]) << 16);
                const int o  = ((cp >> 2) ^ swz)*4 + (cp & 3);
                ldsI[base + o]      = lo;
                ldsI[base + 16 + o] = hi;
            }
        } else {
            #pragma unroll
            for (int cp = 0; cp < 16; ++cp) {
                const int o = ((cp >> 2) ^ swz)*4 + (cp & 3);
                ldsI[base + o] = 0; ldsI[base + 16 + o] = 0;
            }
        }
    }
    __syncthreads();

    // ---- conv1: D1[o][px], bias pre-loaded into acc ------------------------
    f32x4 acc1[4][4];
    #pragma unroll
    for (int mt = 0; mt < 4; ++mt) {
        const f32x4 bv = *(const f32x4*)(b1 + mt*16 + 4*q);
        #pragma unroll
        for (int nt = 0; nt < 4; ++nt) acc1[mt][nt] = bv;
    }

    const short8 zero8 = {0,0,0,0,0,0,0,0};
    #pragma unroll
    for (int tap = 0; tap < 6; ++tap) {
        const int r  = tap / 3;
        const int dw = (tap % 3) - 1;
        short8 wf[4];
        #pragma unroll
        for (int mt = 0; mt < 4; ++mt)
            wf[mt] = *(const short8*)(w1b + (mt*16 + lrow)*192 + tap*32 + q*8);
        #pragma unroll
        for (int nt = 0; nt < 4; ++nt) {
            const int pxo = wv*64 + nt*16 + lrow;
            const int px  = pxo + dw;
            const int pxc = px < 0 ? 0 : (px > 255 ? 255 : px);
            const int byteoff = r*16384 + pxc*64 + ((q ^ ((pxc >> 1) & 3)) << 4);
            short8 xf = *(const short8*)((const char*)ldsI + byteoff);
            if (px != pxc) xf = zero8;
            #pragma unroll
            for (int mt = 0; mt < 4; ++mt)
                acc1[mt][nt] = __builtin_amdgcn_mfma_f32_16x16x32_bf16(
                                   wf[mt], xf, acc1[mt][nt], 0, 0, 0);
        }
    }

    // ---- ELU in-register ---------------------------------------------------
    #pragma unroll
    for (int mt = 0; mt < 4; ++mt)
        #pragma unroll
        for (int nt = 0; nt < 4; ++nt)
            #pragma unroll
            for (int rg = 0; rg < 4; ++rg) {
                const float v = acc1[mt][nt][rg];
                acc1[mt][nt][rg] = v > 0.f ? v : (__expf(v) - 1.f);
            }

    // ---- conv2: lane-local B-frags (hidden dim pre-permuted in w2b) -------
    short8 a2f[2][4];
    #pragma unroll
    for (int kt = 0; kt < 2; ++kt)
        #pragma unroll
        for (int mt2 = 0; mt2 < 4; ++mt2)
            a2f[kt][mt2] = *(const short8*)(w2b + (mt2*16 + lrow)*64 + kt*32 + q*8);

    f32x4 acc2[4][4];
    #pragma unroll
    for (int nt = 0; nt < 4; ++nt) {
        short8 bf0, bf1;
        #pragma unroll
        for (int rg = 0; rg < 4; ++rg) {
            bf0[rg]     = f2bf(acc1[0][nt][rg]);
            bf0[rg + 4] = f2bf(acc1[1][nt][rg]);
            bf1[rg]     = f2bf(acc1[2][nt][rg]);
            bf1[rg + 4] = f2bf(acc1[3][nt][rg]);
        }
        #pragma unroll
        for (int mt2 = 0; mt2 < 4; ++mt2) {
            f32x4 t0 = __builtin_amdgcn_mfma_f32_16x16x32_bf16(
                           a2f[0][mt2], bf0, (f32x4){0.f,0.f,0.f,0.f}, 0, 0, 0);
            acc2[mt2][nt] = __builtin_amdgcn_mfma_f32_16x16x32_bf16(
                           a2f[1][mt2], bf1, t0, 0, 0, 0);
        }
    }

    // ---- epilogue: sigmoid/affine/logdet, all lane-local -------------------
    f32x4 b2m[2], b2s[2];
    #pragma unroll
    for (int mt2 = 0; mt2 < 2; ++mt2) {
        b2m[mt2] = *(const f32x4*)(b2 + mt2*16 + 4*q);
        b2s[mt2] = *(const f32x4*)(b2 + 32 + mt2*16 + 4*q);
    }

    float ldsum = 0.f;
    float* ob = out + (size_t)b * (C_*H_*W_);
    #pragma unroll
    for (int nt = 0; nt < 4; ++nt) {
        const int px = wv*64 + nt*16 + lrow;
        const int colbase = h*W_ + px;
        #pragma unroll
        for (int mt2 = 0; mt2 < 2; ++mt2)
            #pragma unroll
            for (int rg = 0; rg < 4; ++rg) {
                const int j = mt2*16 + 4*q + rg;
                const float mu = acc2[mt2][nt][rg]     + b2m[mt2][rg];
                const float z  = acc2[mt2 + 2][nt][rg] + b2s[mt2][rg] + 2.f;
                const float sc = 1.f / (1.f + __expf(-z));
                ldsum += __logf(sc);
                const size_t idx = (size_t)j * (H_*W_) + colbase;
                ob[idx] = xb[idx] * sc + mu;
            }
    }

    #pragma unroll
    for (int m = 32; m >= 1; m >>= 1) ldsum += __shfl_xor(ldsum, m, 64);
    if (l == 0) red4[wv] = ldsum;
    __syncthreads();
    if (tid == 0) atomicAdd(&logdet[b], red4[0] + red4[1] + red4[2] + red4[3]);
}

// ---------------------------------------------------------------------------
extern "C" void kernel_launch(void* const* d_in, const int* in_sizes, int n_in,
                              void* d_out, int out_size, void* d_ws, size_t ws_size,
                              hipStream_t stream)
{
    const float* x  = (const float*)d_in[0];
    const float* v1 = (const float*)d_in[1];
    const float* g1 = (const float*)d_in[2];
    const float* b1 = (const float*)d_in[3];
    const float* v2 = (const float*)d_in[4];
    const float* g2 = (const float*)d_in[5];
    const float* b2 = (const float*)d_in[6];

    float* out    = (float*)d_out;
    float* logdet = out + NPIX;

    short* w1b = (short*)d_ws;          // 12288 bf16
    short* w2b = w1b + 12288;           //  4096 bf16

    prep_kernel<<<128, 64, 0, stream>>>(v1, g1, v2, g2, w1b, w2b, logdet);
    flow_kernel<<<B_ * H_, 256, 0, stream>>>(x, w1b, w2b, b1, b2, out, logdet);
}